// Round 2
// baseline (330.723 us; speedup 1.0000x reference)
//
#include <hip/hip_runtime.h>
#include <cstddef>

#define HB 64
#define HN_PER 4096
#define HN_TOOL 1000
#define HD 128
#define HT 50
#define HSCALE 50.0f

typedef _Float16 f16x8 __attribute__((ext_vector_type(8)));
typedef float f32x4 __attribute__((ext_vector_type(4)));

constexpr int TILE_M = 64;
constexpr int APITCH = 136;                     // fp16 LDS row pitch
constexpr int SPITCH = 204;                     // float stage row pitch (204%32=12 -> conflict-light, 16B-aligned rows)

// fp16 swizzled weights live in ws halves [0, 53248) = bytes [0, 106496)
constexpr int W1_BASE = 0;
constexpr int W2_BASE = 16384;
constexpr int W3_BASE = 32768;     // 40 frags -> ends at 53248 halves

// float-indexed ws regions (after the fp16 weights)
constexpr int XC0_F = 26624;                    // [B][N][3] centered scaled pos
constexpr int C0_F  = XC0_F + HB * HN_TOOL * 3; // [B][9]  Xc0^T Xc0
constexpr int BT_F  = C0_F + HB * 9;            // [B*T][12]: B (9) + sum_f (3)  (atomically accumulated)
constexpr int MT_F  = BT_F + HB * HT * 12;      // [B*T][12]: P_{t+1}-P_t (9) + mf (3)

// ---------------------------------------------------------------------------
// Wave64 sum, valid in every lane (row_ror rotations + shfl_xor).
// ---------------------------------------------------------------------------
__device__ __forceinline__ float wave_red_sum(float v)
{
#define DPP_ADD(ctrl)                                                          \
    v += __builtin_bit_cast(float, __builtin_amdgcn_update_dpp(                \
             0, __builtin_bit_cast(int, v), (ctrl), 0xF, 0xF, true));
    DPP_ADD(0x128)   // row_ror:8
    DPP_ADD(0x124)   // row_ror:4
    DPP_ADD(0x122)   // row_ror:2
    DPP_ADD(0x121)   // row_ror:1
#undef DPP_ADD
    v += __shfl_xor(v, 16, 64);
    v += __shfl_xor(v, 32, 64);
    return v;
}

// ---------------------------------------------------------------------------
// prep: blocks 0..63  -> init (gather pos, mu0, xc0, C0) for batch b=blk
//       blocks 64..89 -> weight fp32->fp16 swizzle (4 fragment-waves each)
//       block  90     -> zero the BT accumulator region
// ---------------------------------------------------------------------------
__global__ __launch_bounds__(256) void prep_kernel(
    const float* __restrict__ pos,
    const int* __restrict__ tool_idx,
    const float* __restrict__ W1, const float* __restrict__ W2,
    const float* __restrict__ W3,
    _Float16* __restrict__ wsh, float* __restrict__ wsf)
{
    __shared__ float red[4][6];
    const int blk = blockIdx.x;
    const int tid = threadIdx.x;

    if (blk < 64) {
        // ---------------- init for batch b ----------------
        const int b = blk;
        const int lane = tid & 63, wv = tid >> 6;
        const int nb = tid * 4;                 // 4 consecutive points/thread
        const bool act = nb < HN_TOOL;          // threads 0..249 active

        float xv[4], yv[4], zv[4];
        if (act) {
            const int4 i4 = *(const int4*)(tool_idx + b * HN_TOOL + nb);
            const int pi[4] = {i4.x, i4.y, i4.z, i4.w};
#pragma unroll
            for (int s = 0; s < 4; ++s) {
                const float* pp = pos + (size_t)(b * HN_PER + pi[s]) * 3;
                xv[s] = pp[0] * HSCALE;
                yv[s] = pp[1] * HSCALE;
                zv[s] = pp[2] * HSCALE;
            }
        }
        float s0 = 0.f, s1 = 0.f, s2 = 0.f;
        if (act) {
#pragma unroll
            for (int s = 0; s < 4; ++s) { s0 += xv[s]; s1 += yv[s]; s2 += zv[s]; }
        }
        s0 = wave_red_sum(s0); s1 = wave_red_sum(s1); s2 = wave_red_sum(s2);
        if (lane == 0) { red[wv][0] = s0; red[wv][1] = s1; red[wv][2] = s2; }
        __syncthreads();
        const float invN = 1.0f / HN_TOOL;
        const float mux = (red[0][0] + red[1][0] + red[2][0] + red[3][0]) * invN;
        const float muy = (red[0][1] + red[1][1] + red[2][1] + red[3][1]) * invN;
        const float muz = (red[0][2] + red[1][2] + red[2][2] + red[3][2]) * invN;
        __syncthreads();

        float xx = 0.f, xy = 0.f, xz = 0.f, yy = 0.f, yz = 0.f, zz = 0.f;
        if (act) {
            float o[12];
#pragma unroll
            for (int s = 0; s < 4; ++s) {
                const float x = xv[s] - mux, y = yv[s] - muy, z = zv[s] - muz;
                o[3 * s + 0] = x; o[3 * s + 1] = y; o[3 * s + 2] = z;
                xx += x * x; xy += x * y; xz += x * z;
                yy += y * y; yz += y * z; zz += z * z;
            }
            float4* dst = (float4*)(wsf + XC0_F + (size_t)b * (HN_TOOL * 3) + nb * 3);
            dst[0] = *(float4*)&o[0];
            dst[1] = *(float4*)&o[4];
            dst[2] = *(float4*)&o[8];
        }
        float c6[6] = {xx, xy, xz, yy, yz, zz};
#pragma unroll
        for (int v = 0; v < 6; ++v) c6[v] = wave_red_sum(c6[v]);
        if (lane == 0) {
#pragma unroll
            for (int v = 0; v < 6; ++v) red[wv][v] = c6[v];
        }
        __syncthreads();
        if (tid == 0) {
            float g[6];
#pragma unroll
            for (int v = 0; v < 6; ++v)
                g[v] = red[0][v] + red[1][v] + red[2][v] + red[3][v];
            float* c0 = wsf + C0_F + b * 9;
            c0[0] = g[0]; c0[1] = g[1]; c0[2] = g[2];
            c0[3] = g[1]; c0[4] = g[3]; c0[5] = g[4];
            c0[6] = g[2]; c0[7] = g[4]; c0[8] = g[5];
        }
    } else if (blk < 90) {
        // ---------------- weight conversion ----------------
        const int lane = tid & 63;
        const int f = (blk - 64) * 4 + (tid >> 6);   // 0..103
        const float* W; int ncols, base, fi;
        if (f < 32)       { W = W1; ncols = 128; base = W1_BASE; fi = f; }
        else if (f < 64)  { W = W2; ncols = 128; base = W2_BASE; fi = f - 32; }
        else              { W = W3; ncols = 150; base = W3_BASE; fi = f - 64; }
        const int nt = fi >> 2, kc = fi & 3;
        const int col = nt * 16 + (lane & 15);
        const int k0 = kc * 32 + (lane >> 4) * 8;
        f16x8 v;
#pragma unroll
        for (int j = 0; j < 8; ++j)
            v[j] = (col < ncols) ? (_Float16)W[(size_t)(k0 + j) * ncols + col]
                                 : (_Float16)0.f;
        *(f16x8*)(wsh + ((size_t)(base + (fi * 64 + lane) * 8))) = v;
    } else {
        // ---------------- zero BT accumulators ----------------
        const float4 z4 = {0.f, 0.f, 0.f, 0.f};
        float4* bt4 = (float4*)(wsf + BT_F);
        for (int i = tid; i < (HB * HT * 12) / 4; i += 256) bt4[i] = z4;
    }
}

// ---------------------------------------------------------------------------
// Kernel 1: gather -> 3-layer MLP via fp16 MFMA -> LDS-staged coalesced store
// into out2 ([B][T][N][3]) + fused moment reduction (B = Xc0^T F, sum_f)
// accumulated into ws BT via atomics.
// Grid: dim3(16, 64) — 16 blocks of 64 rows per batch (last block 40 valid).
// ---------------------------------------------------------------------------
__global__ __launch_bounds__(256) void mlp_mfma_kernel(
    const float* __restrict__ x_feat,
    const int* __restrict__ tool_idx,
    const _Float16* __restrict__ Wsw,
    const float* __restrict__ b1, const float* __restrict__ b2,
    const float* __restrict__ b3,
    float* __restrict__ out2, float* __restrict__ wsf)
{
    // hA (64x136 fp16 = 17408 B) lives during the 3 layers;
    // stage (50x204 f32 = 40800 B) aliases it after the last hA read.
    __shared__ __align__(16) char smem[HT * SPITCH * 4];
    _Float16 (*hA)[APITCH] = (_Float16 (*)[APITCH])smem;
    float* stage = (float*)smem;

    const int tid = threadIdx.x;
    const int lane = tid & 63, w = tid >> 6;
    const int lm = lane & 15, quad = lane >> 4;
    const int m0 = w * 16;
    const int bx = blockIdx.x;                 // 0..15 within batch
    const int b  = blockIdx.y;                 // batch
    const int n0 = bx * TILE_M;

    {
        const int i = tid >> 2;
        const int c0 = (tid & 3) * 32;
        const int n = n0 + i;
        const int nc = (n < HN_TOOL) ? n : (HN_TOOL - 1);   // clamp pad rows
        const int p = tool_idx[b * HN_TOOL + nc];
        const float4* src =
            (const float4*)(x_feat + (size_t)(b * HN_PER + p) * HD + c0);
#pragma unroll
        for (int fq = 0; fq < 4; ++fq) {
            const float4 u = src[2 * fq], v = src[2 * fq + 1];
            f16x8 h = {(_Float16)u.x, (_Float16)u.y, (_Float16)u.z, (_Float16)u.w,
                       (_Float16)v.x, (_Float16)v.y, (_Float16)v.z, (_Float16)v.w};
            *(f16x8*)&hA[i][c0 + fq * 8] = h;
        }
    }
    __syncthreads();

    // layers 1,2: each wave owns its 16 rows end-to-end (no cross-wave dep)
#pragma unroll
    for (int layer = 0; layer < 2; ++layer) {
        const _Float16* wb = Wsw + (layer ? W2_BASE : W1_BASE);
        const float* bias = layer ? b2 : b1;
        f16x8 afr[4];
#pragma unroll
        for (int kc = 0; kc < 4; ++kc)
            afr[kc] = *(const f16x8*)&hA[m0 + lm][kc * 32 + quad * 8];
        f32x4 acc[8];
#pragma unroll
        for (int nt = 0; nt < 8; ++nt) acc[nt] = (f32x4){0.f, 0.f, 0.f, 0.f};
#pragma unroll
        for (int kc = 0; kc < 4; ++kc)
#pragma unroll
            for (int nt = 0; nt < 8; ++nt) {
                const f16x8 bf = *(const f16x8*)(wb + (size_t)((nt * 4 + kc) * 64 + lane) * 8);
                acc[nt] = __builtin_amdgcn_mfma_f32_16x16x32_f16(afr[kc], bf, acc[nt], 0, 0, 0);
            }
#pragma unroll
        for (int nt = 0; nt < 8; ++nt) {
            const float bb = bias[nt * 16 + lm];
#pragma unroll
            for (int r = 0; r < 4; ++r)
                hA[m0 + quad * 4 + r][nt * 16 + lm] =
                    (_Float16)fmaxf(acc[nt][r] + bb, 0.f);
        }
    }

    // layer 3 + staged epilogue
    {
        f16x8 afr[4];
#pragma unroll
        for (int kc = 0; kc < 4; ++kc)
            afr[kc] = *(const f16x8*)&hA[m0 + lm][kc * 32 + quad * 8];
        __syncthreads();   // all hA reads done before stage aliases it
        f32x4 acc[10];
#pragma unroll
        for (int nt = 0; nt < 10; ++nt) acc[nt] = (f32x4){0.f, 0.f, 0.f, 0.f};
#pragma unroll
        for (int kc = 0; kc < 4; ++kc)
#pragma unroll
            for (int nt = 0; nt < 10; ++nt) {
                const f16x8 bf = *(const f16x8*)(Wsw + W3_BASE + (size_t)((nt * 4 + kc) * 64 + lane) * 8);
                acc[nt] = __builtin_amdgcn_mfma_f32_16x16x32_f16(afr[kc], bf, acc[nt], 0, 0, 0);
            }
        // write flow values transposed into stage[t][i*3+c]
#pragma unroll
        for (int nt = 0; nt < 10; ++nt) {
            const int j = nt * 16 + lm;
            if (j < 150) {
                const float bb = b3[j];
                const int t = j / 3, c = j - 3 * t;
#pragma unroll
                for (int r = 0; r < 4; ++r)
                    stage[t * SPITCH + (m0 + quad * 4 + r) * 3 + c] = acc[nt][r] + bb;
            }
        }
    }
    __syncthreads();

    // coalesced non-temporal out2 store: per t, one contiguous 3*V-float chunk
    const int V = (bx == 15) ? (HN_TOOL - 15 * TILE_M) : TILE_M;   // 40 or 64
    const int nf4 = (V * 3) >> 2;                                   // 30 or 48
    {
        float* ob = out2 + (size_t)b * HT * (HN_TOOL * 3) + (size_t)n0 * 3;
        for (int t = w; t < HT; t += 4) {
            if (lane < nf4) {
                const f32x4 v = *(const f32x4*)&stage[t * SPITCH + lane * 4];
                __builtin_nontemporal_store(
                    v, (f32x4*)(ob + (size_t)t * (HN_TOOL * 3)) + lane);
            }
        }
    }

    // fused moment reduction: threads 0..199, 4 threads (16 rows each) per t
    if (tid < 4 * HT) {
        const int t = tid >> 2, part = tid & 3;
        const float* xc = wsf + XC0_F + (size_t)b * (HN_TOOL * 3) + (size_t)n0 * 3;
        float S[12];
#pragma unroll
        for (int v = 0; v < 12; ++v) S[v] = 0.f;
#pragma unroll
        for (int rr = 0; rr < 16; ++rr) {
            const int nl = part * 16 + rr;
            if (n0 + nl < HN_TOOL) {
                const float x = xc[3 * nl + 0], y = xc[3 * nl + 1], z = xc[3 * nl + 2];
                const float fx = stage[t * SPITCH + 3 * nl + 0];
                const float fy = stage[t * SPITCH + 3 * nl + 1];
                const float fz = stage[t * SPITCH + 3 * nl + 2];
                S[0] += x * fx; S[1] += x * fy; S[2] += x * fz;
                S[3] += y * fx; S[4] += y * fy; S[5] += y * fz;
                S[6] += z * fx; S[7] += z * fy; S[8] += z * fz;
                S[9] += fx; S[10] += fy; S[11] += fz;
            }
        }
#pragma unroll
        for (int v = 0; v < 12; ++v) {
            S[v] += __shfl_xor(S[v], 1, 64);
            S[v] += __shfl_xor(S[v], 2, 64);
        }
        if (part == 0) {
            float* btp = wsf + BT_F + ((size_t)b * HT + t) * 12;
#pragma unroll
            for (int v = 0; v < 12; ++v) atomicAdd(btp + v, S[v]);
        }
    }
}

// ---------------------------------------------------------------------------
// compose: one lane per batch (single wave). Sequential over t:
//   H = P^T (C0 P + B); R = polar(H) by 2 Newton iters; M = P(R-I); P = P R.
// ---------------------------------------------------------------------------
__global__ __launch_bounds__(64) void compose_kernel(float* __restrict__ ws)
{
    const int b = threadIdx.x;
    float C0[9], P[9];
#pragma unroll
    for (int v = 0; v < 9; ++v) C0[v] = ws[C0_F + b * 9 + v];
    P[0] = 1.f; P[1] = 0.f; P[2] = 0.f;
    P[3] = 0.f; P[4] = 1.f; P[5] = 0.f;
    P[6] = 0.f; P[7] = 0.f; P[8] = 1.f;

    const float invN = 1.0f / HN_TOOL;
    const float* bt = ws + BT_F + (size_t)b * HT * 12;
    float* mt = ws + MT_F + (size_t)b * HT * 12;

    float4 n0 = *(const float4*)(bt);
    float4 n1 = *(const float4*)(bt + 4);
    float4 n2 = *(const float4*)(bt + 8);

    for (int t = 0; t < HT; ++t) {
        const float Bv[12] = {n0.x, n0.y, n0.z, n0.w, n1.x, n1.y, n1.z, n1.w,
                              n2.x, n2.y, n2.z, n2.w};
        if (t + 1 < HT) {
            const float* nb = bt + (t + 1) * 12;
            n0 = *(const float4*)(nb);
            n1 = *(const float4*)(nb + 4);
            n2 = *(const float4*)(nb + 8);
        }
        // G = C0*P + B
        float G[9];
#pragma unroll
        for (int i = 0; i < 3; ++i)
#pragma unroll
            for (int j = 0; j < 3; ++j)
                G[i * 3 + j] = C0[i * 3 + 0] * P[0 * 3 + j] +
                               C0[i * 3 + 1] * P[1 * 3 + j] +
                               C0[i * 3 + 2] * P[2 * 3 + j] + Bv[i * 3 + j];
        // H = P^T * G
        float X[9];
#pragma unroll
        for (int i = 0; i < 3; ++i)
#pragma unroll
            for (int j = 0; j < 3; ++j)
                X[i * 3 + j] = P[0 * 3 + i] * G[0 * 3 + j] +
                               P[1 * 3 + i] * G[1 * 3 + j] +
                               P[2 * 3 + i] * G[2 * 3 + j];
        const float scl = 3.0f * __builtin_amdgcn_rcpf(X[0] + X[4] + X[8]);
#pragma unroll
        for (int v = 0; v < 9; ++v) X[v] *= scl;
        // 2 Newton polar iters
#pragma unroll
        for (int it = 0; it < 2; ++it) {
            float C[9];
            C[0] =  (X[4] * X[8] - X[5] * X[7]);
            C[1] = -(X[3] * X[8] - X[5] * X[6]);
            C[2] =  (X[3] * X[7] - X[4] * X[6]);
            C[3] = -(X[1] * X[8] - X[2] * X[7]);
            C[4] =  (X[0] * X[8] - X[2] * X[6]);
            C[5] = -(X[0] * X[7] - X[1] * X[6]);
            C[6] =  (X[1] * X[5] - X[2] * X[4]);
            C[7] = -(X[0] * X[5] - X[2] * X[3]);
            C[8] =  (X[0] * X[4] - X[1] * X[3]);
            const float det = X[0] * C[0] + X[1] * C[1] + X[2] * C[2];
            const float rdet = 0.5f * __builtin_amdgcn_rcpf(det);
#pragma unroll
            for (int v = 0; v < 9; ++v) X[v] = 0.5f * X[v] + C[v] * rdet;
        }
        // Pn = P * R (R = X); M = Pn - P
        float Pn[9];
#pragma unroll
        for (int i = 0; i < 3; ++i)
#pragma unroll
            for (int j = 0; j < 3; ++j)
                Pn[i * 3 + j] = P[i * 3 + 0] * X[0 * 3 + j] +
                                P[i * 3 + 1] * X[1 * 3 + j] +
                                P[i * 3 + 2] * X[2 * 3 + j];
        float4 m0, m1, m2;
        m0.x = Pn[0] - P[0]; m0.y = Pn[1] - P[1]; m0.z = Pn[2] - P[2];
        m0.w = Pn[3] - P[3]; m1.x = Pn[4] - P[4]; m1.y = Pn[5] - P[5];
        m1.z = Pn[6] - P[6]; m1.w = Pn[7] - P[7]; m2.x = Pn[8] - P[8];
        m2.y = Bv[9] * invN; m2.z = Bv[10] * invN; m2.w = Bv[11] * invN;
        float* mo = mt + t * 12;
        *(float4*)(mo) = m0;
        *(float4*)(mo + 4) = m1;
        *(float4*)(mo + 8) = m2;
#pragma unroll
        for (int v = 0; v < 9; ++v) P[v] = Pn[v];
    }
}

// ---------------------------------------------------------------------------
// apply: out1[b][t][n] = xc0[b][n] * M[b][t] + mf[b][t]. float4 in, f32x4
// non-temporal out.
// ---------------------------------------------------------------------------
__global__ __launch_bounds__(256) void apply_kernel(
    const float* __restrict__ ws, float* __restrict__ out1)
{
    __shared__ float M[12];
    const int t = blockIdx.x, b = blockIdx.y;
    const int tid = threadIdx.x;
    if (tid < 12) M[tid] = ws[MT_F + (size_t)(b * HT + t) * 12 + tid];
    __syncthreads();

    const int nb = tid * 4;                    // 4 consecutive points/thread
    if (nb < HN_TOOL) {
        const float4* xc4 =
            (const float4*)(ws + XC0_F + (size_t)b * (HN_TOOL * 3) + nb * 3);
        float in12[12], o12[12];
        *(float4*)&in12[0] = xc4[0];
        *(float4*)&in12[4] = xc4[1];
        *(float4*)&in12[8] = xc4[2];
#pragma unroll
        for (int k = 0; k < 4; ++k) {
            const float x = in12[3 * k], y = in12[3 * k + 1], z = in12[3 * k + 2];
            o12[3 * k + 0] = x * M[0] + y * M[3] + z * M[6] + M[9];
            o12[3 * k + 1] = x * M[1] + y * M[4] + z * M[7] + M[10];
            o12[3 * k + 2] = x * M[2] + y * M[5] + z * M[8] + M[11];
        }
        f32x4* ot = (f32x4*)(out1 + ((size_t)(b * HT + t) * HN_TOOL) * 3 + nb * 3);
        __builtin_nontemporal_store(*(f32x4*)&o12[0], ot + 0);
        __builtin_nontemporal_store(*(f32x4*)&o12[4], ot + 1);
        __builtin_nontemporal_store(*(f32x4*)&o12[8], ot + 2);
    }
}

// ---------------------------------------------------------------------------
extern "C" void kernel_launch(void* const* d_in, const int* in_sizes, int n_in,
                              void* d_out, int out_size, void* d_ws, size_t ws_size,
                              hipStream_t stream)
{
    const float* x_feat   = (const float*)d_in[0];
    const float* pos      = (const float*)d_in[1];
    const int*   tool_idx = (const int*)d_in[2];
    const float* W1 = (const float*)d_in[3];
    const float* b1 = (const float*)d_in[4];
    const float* W2 = (const float*)d_in[5];
    const float* b2 = (const float*)d_in[6];
    const float* W3 = (const float*)d_in[7];
    const float* b3 = (const float*)d_in[8];

    float* out1 = (float*)d_out;                               // flow_traj
    float* out2 = out1 + (size_t)HB * HT * HN_TOOL * 3;        // before_svd
    _Float16* wsw = (_Float16*)d_ws;
    float* wsf = (float*)d_ws;

    prep_kernel<<<91, 256, 0, stream>>>(pos, tool_idx, W1, W2, W3, wsw, wsf);
    mlp_mfma_kernel<<<dim3(16, HB), 256, 0, stream>>>(
        x_feat, tool_idx, wsw, b1, b2, b3, out2, wsf);
    compose_kernel<<<1, 64, 0, stream>>>(wsf);
    apply_kernel<<<dim3(HT, HB), 256, 0, stream>>>(wsf, out1);
}

// Round 3
// 320.819 us; speedup vs baseline: 1.0309x; 1.0309x over previous
//
#include <hip/hip_runtime.h>
#include <cstddef>

#define HB 64
#define HN_PER 4096
#define HN_TOOL 1000
#define HD 128
#define HT 50
#define HSCALE 50.0f

typedef _Float16 f16x8 __attribute__((ext_vector_type(8)));
typedef float f32x4 __attribute__((ext_vector_type(4)));

constexpr int TILE_M = 64;
constexpr int APITCH = 136;                     // fp16 LDS row pitch
constexpr int SPITCH = 204;                     // float stage row pitch
constexpr int THALF = 25;                       // timesteps staged per half

// fp16 swizzled weights live in ws halves [0, 53248) = bytes [0, 106496)
constexpr int W1_BASE = 0;
constexpr int W2_BASE = 16384;
constexpr int W3_BASE = 32768;     // 40 frags -> ends at 53248 halves

// float-indexed ws regions (after the fp16 weights)
constexpr int XC0_F = 26624;                    // [B][N][3] centered scaled pos
constexpr int C0_F  = XC0_F + HB * HN_TOOL * 3; // [B][9]  Xc0^T Xc0
constexpr int BT_F  = C0_F + HB * 9;            // [B*T][12]: B (9) + sum_f (3)  (atomically accumulated)
constexpr int MT_F  = BT_F + HB * HT * 12;      // [B*T][12]: P_{t+1}-P_t (9) + mf (3)

// ---------------------------------------------------------------------------
// Wave64 sum, valid in every lane (row_ror rotations + shfl_xor).
// ---------------------------------------------------------------------------
__device__ __forceinline__ float wave_red_sum(float v)
{
#define DPP_ADD(ctrl)                                                          \
    v += __builtin_bit_cast(float, __builtin_amdgcn_update_dpp(                \
             0, __builtin_bit_cast(int, v), (ctrl), 0xF, 0xF, true));
    DPP_ADD(0x128)   // row_ror:8
    DPP_ADD(0x124)   // row_ror:4
    DPP_ADD(0x122)   // row_ror:2
    DPP_ADD(0x121)   // row_ror:1
#undef DPP_ADD
    v += __shfl_xor(v, 16, 64);
    v += __shfl_xor(v, 32, 64);
    return v;
}

// ---------------------------------------------------------------------------
// prep: blocks 0..63  -> init (gather pos, mu0, xc0, C0) for batch b=blk
//       blocks 64..89 -> weight fp32->fp16 swizzle (4 fragment-waves each)
//       block  90     -> zero the BT accumulator region
// ---------------------------------------------------------------------------
__global__ __launch_bounds__(256) void prep_kernel(
    const float* __restrict__ pos,
    const int* __restrict__ tool_idx,
    const float* __restrict__ W1, const float* __restrict__ W2,
    const float* __restrict__ W3,
    _Float16* __restrict__ wsh, float* __restrict__ wsf)
{
    __shared__ float red[4][6];
    const int blk = blockIdx.x;
    const int tid = threadIdx.x;

    if (blk < 64) {
        // ---------------- init for batch b ----------------
        const int b = blk;
        const int lane = tid & 63, wv = tid >> 6;
        const int nb = tid * 4;                 // 4 consecutive points/thread
        const bool act = nb < HN_TOOL;          // threads 0..249 active

        float xv[4], yv[4], zv[4];
        if (act) {
            const int4 i4 = *(const int4*)(tool_idx + b * HN_TOOL + nb);
            const int pi[4] = {i4.x, i4.y, i4.z, i4.w};
#pragma unroll
            for (int s = 0; s < 4; ++s) {
                const float* pp = pos + (size_t)(b * HN_PER + pi[s]) * 3;
                xv[s] = pp[0] * HSCALE;
                yv[s] = pp[1] * HSCALE;
                zv[s] = pp[2] * HSCALE;
            }
        }
        float s0 = 0.f, s1 = 0.f, s2 = 0.f;
        if (act) {
#pragma unroll
            for (int s = 0; s < 4; ++s) { s0 += xv[s]; s1 += yv[s]; s2 += zv[s]; }
        }
        s0 = wave_red_sum(s0); s1 = wave_red_sum(s1); s2 = wave_red_sum(s2);
        if (lane == 0) { red[wv][0] = s0; red[wv][1] = s1; red[wv][2] = s2; }
        __syncthreads();
        const float invN = 1.0f / HN_TOOL;
        const float mux = (red[0][0] + red[1][0] + red[2][0] + red[3][0]) * invN;
        const float muy = (red[0][1] + red[1][1] + red[2][1] + red[3][1]) * invN;
        const float muz = (red[0][2] + red[1][2] + red[2][2] + red[3][2]) * invN;
        __syncthreads();

        float xx = 0.f, xy = 0.f, xz = 0.f, yy = 0.f, yz = 0.f, zz = 0.f;
        if (act) {
            float o[12];
#pragma unroll
            for (int s = 0; s < 4; ++s) {
                const float x = xv[s] - mux, y = yv[s] - muy, z = zv[s] - muz;
                o[3 * s + 0] = x; o[3 * s + 1] = y; o[3 * s + 2] = z;
                xx += x * x; xy += x * y; xz += x * z;
                yy += y * y; yz += y * z; zz += z * z;
            }
            float4* dst = (float4*)(wsf + XC0_F + (size_t)b * (HN_TOOL * 3) + nb * 3);
            dst[0] = *(float4*)&o[0];
            dst[1] = *(float4*)&o[4];
            dst[2] = *(float4*)&o[8];
        }
        float c6[6] = {xx, xy, xz, yy, yz, zz};
#pragma unroll
        for (int v = 0; v < 6; ++v) c6[v] = wave_red_sum(c6[v]);
        if (lane == 0) {
#pragma unroll
            for (int v = 0; v < 6; ++v) red[wv][v] = c6[v];
        }
        __syncthreads();
        if (tid == 0) {
            float g[6];
#pragma unroll
            for (int v = 0; v < 6; ++v)
                g[v] = red[0][v] + red[1][v] + red[2][v] + red[3][v];
            float* c0 = wsf + C0_F + b * 9;
            c0[0] = g[0]; c0[1] = g[1]; c0[2] = g[2];
            c0[3] = g[1]; c0[4] = g[3]; c0[5] = g[4];
            c0[6] = g[2]; c0[7] = g[4]; c0[8] = g[5];
        }
    } else if (blk < 90) {
        // ---------------- weight conversion ----------------
        const int lane = tid & 63;
        const int f = (blk - 64) * 4 + (tid >> 6);   // 0..103
        const float* W; int ncols, base, fi;
        if (f < 32)       { W = W1; ncols = 128; base = W1_BASE; fi = f; }
        else if (f < 64)  { W = W2; ncols = 128; base = W2_BASE; fi = f - 32; }
        else              { W = W3; ncols = 150; base = W3_BASE; fi = f - 64; }
        const int nt = fi >> 2, kc = fi & 3;
        const int col = nt * 16 + (lane & 15);
        const int k0 = kc * 32 + (lane >> 4) * 8;
        f16x8 v;
#pragma unroll
        for (int j = 0; j < 8; ++j)
            v[j] = (col < ncols) ? (_Float16)W[(size_t)(k0 + j) * ncols + col]
                                 : (_Float16)0.f;
        *(f16x8*)(wsh + ((size_t)(base + (fi * 64 + lane) * 8))) = v;
    } else {
        // ---------------- zero BT accumulators ----------------
        const float4 z4 = {0.f, 0.f, 0.f, 0.f};
        float4* bt4 = (float4*)(wsf + BT_F);
        for (int i = tid; i < (HB * HT * 12) / 4; i += 256) bt4[i] = z4;
    }
}

// ---------------------------------------------------------------------------
// Kernel 1: gather -> 3-layer MLP via fp16 MFMA -> LDS-staged coalesced store
// into out2 ([B][T][N][3]) + fused moment reduction (B = Xc0^T F, sum_f)
// accumulated into ws BT via atomics.
// Grid: dim3(16, 64) — 16 blocks of 64 rows per batch (last block 40 valid).
// Epilogue staged in TWO halves of 25 timesteps so LDS stays at 20.4 KB
// (union with hA) -> 7 blocks/CU instead of 2.
// ---------------------------------------------------------------------------
__global__ __launch_bounds__(256, 7) void mlp_mfma_kernel(
    const float* __restrict__ x_feat,
    const int* __restrict__ tool_idx,
    const _Float16* __restrict__ Wsw,
    const float* __restrict__ b1, const float* __restrict__ b2,
    const float* __restrict__ b3,
    float* __restrict__ out2, float* __restrict__ wsf)
{
    // hA (64x136 fp16 = 17408 B) lives during the 3 layers;
    // stage (25x204 f32 = 20400 B) aliases it after the last hA read.
    __shared__ __align__(16) char smem[THALF * SPITCH * 4];
    _Float16 (*hA)[APITCH] = (_Float16 (*)[APITCH])smem;
    float* stage = (float*)smem;

    const int tid = threadIdx.x;
    const int lane = tid & 63, w = tid >> 6;
    const int lm = lane & 15, quad = lane >> 4;
    const int m0 = w * 16;
    const int bx = blockIdx.x;                 // 0..15 within batch
    const int b  = blockIdx.y;                 // batch
    const int n0 = bx * TILE_M;

    {
        const int i = tid >> 2;
        const int c0 = (tid & 3) * 32;
        const int n = n0 + i;
        const int nc = (n < HN_TOOL) ? n : (HN_TOOL - 1);   // clamp pad rows
        const int p = tool_idx[b * HN_TOOL + nc];
        const float4* src =
            (const float4*)(x_feat + (size_t)(b * HN_PER + p) * HD + c0);
#pragma unroll
        for (int fq = 0; fq < 4; ++fq) {
            const float4 u = src[2 * fq], v = src[2 * fq + 1];
            f16x8 h = {(_Float16)u.x, (_Float16)u.y, (_Float16)u.z, (_Float16)u.w,
                       (_Float16)v.x, (_Float16)v.y, (_Float16)v.z, (_Float16)v.w};
            *(f16x8*)&hA[i][c0 + fq * 8] = h;
        }
    }
    __syncthreads();

    // layers 1,2: each wave owns its 16 rows end-to-end (no cross-wave dep)
#pragma unroll
    for (int layer = 0; layer < 2; ++layer) {
        const _Float16* wb = Wsw + (layer ? W2_BASE : W1_BASE);
        const float* bias = layer ? b2 : b1;
        f16x8 afr[4];
#pragma unroll
        for (int kc = 0; kc < 4; ++kc)
            afr[kc] = *(const f16x8*)&hA[m0 + lm][kc * 32 + quad * 8];
        f32x4 acc[8];
#pragma unroll
        for (int nt = 0; nt < 8; ++nt) acc[nt] = (f32x4){0.f, 0.f, 0.f, 0.f};
#pragma unroll
        for (int kc = 0; kc < 4; ++kc)
#pragma unroll
            for (int nt = 0; nt < 8; ++nt) {
                const f16x8 bf = *(const f16x8*)(wb + (size_t)((nt * 4 + kc) * 64 + lane) * 8);
                acc[nt] = __builtin_amdgcn_mfma_f32_16x16x32_f16(afr[kc], bf, acc[nt], 0, 0, 0);
            }
#pragma unroll
        for (int nt = 0; nt < 8; ++nt) {
            const float bb = bias[nt * 16 + lm];
#pragma unroll
            for (int r = 0; r < 4; ++r)
                hA[m0 + quad * 4 + r][nt * 16 + lm] =
                    (_Float16)fmaxf(acc[nt][r] + bb, 0.f);
        }
    }

    // layer 3
    f32x4 acc[10];
    {
        f16x8 afr[4];
#pragma unroll
        for (int kc = 0; kc < 4; ++kc)
            afr[kc] = *(const f16x8*)&hA[m0 + lm][kc * 32 + quad * 8];
        __syncthreads();   // all hA reads done before stage aliases it
#pragma unroll
        for (int nt = 0; nt < 10; ++nt) acc[nt] = (f32x4){0.f, 0.f, 0.f, 0.f};
#pragma unroll
        for (int kc = 0; kc < 4; ++kc)
#pragma unroll
            for (int nt = 0; nt < 10; ++nt) {
                const f16x8 bf = *(const f16x8*)(Wsw + W3_BASE + (size_t)((nt * 4 + kc) * 64 + lane) * 8);
                acc[nt] = __builtin_amdgcn_mfma_f32_16x16x32_f16(afr[kc], bf, acc[nt], 0, 0, 0);
            }
    }

    // epilogue in two halves of 25 timesteps each
    const int V = (bx == 15) ? (HN_TOOL - 15 * TILE_M) : TILE_M;   // 40 or 64
    const int nf4 = (V * 3) >> 2;                                   // 30 or 48
#pragma unroll
    for (int h = 0; h < 2; ++h) {
        const int t0 = h * THALF;
        // write flow values for this half transposed into stage[t-t0][i*3+c]
#pragma unroll
        for (int nt = 0; nt < 10; ++nt) {
            const int j = nt * 16 + lm;
            if (j < 150) {
                const int t = j / 3, c = j - 3 * t;
                if (t >= t0 && t < t0 + THALF) {
                    const float bb = b3[j];
#pragma unroll
                    for (int r = 0; r < 4; ++r)
                        stage[(t - t0) * SPITCH + (m0 + quad * 4 + r) * 3 + c] =
                            acc[nt][r] + bb;
                }
            }
        }
        __syncthreads();

        // coalesced non-temporal out2 store for this half
        {
            float* ob = out2 + (size_t)b * HT * (HN_TOOL * 3) + (size_t)n0 * 3;
            for (int t = t0 + w; t < t0 + THALF; t += 4) {
                if (lane < nf4) {
                    const f32x4 v =
                        *(const f32x4*)&stage[(t - t0) * SPITCH + lane * 4];
                    __builtin_nontemporal_store(
                        v, (f32x4*)(ob + (size_t)t * (HN_TOOL * 3)) + lane);
                }
            }
        }

        // fused moment reduction for this half: 4 threads (16 rows each) per t
        if (tid < 4 * HT) {
            const int t = tid >> 2;
            if (t >= t0 && t < t0 + THALF) {
                const int part = tid & 3;
                const float* xc =
                    wsf + XC0_F + (size_t)b * (HN_TOOL * 3) + (size_t)n0 * 3;
                float S[12];
#pragma unroll
                for (int v = 0; v < 12; ++v) S[v] = 0.f;
#pragma unroll
                for (int rr = 0; rr < 16; ++rr) {
                    const int nl = part * 16 + rr;
                    if (n0 + nl < HN_TOOL) {
                        const float x = xc[3 * nl + 0], y = xc[3 * nl + 1],
                                    z = xc[3 * nl + 2];
                        const float fx = stage[(t - t0) * SPITCH + 3 * nl + 0];
                        const float fy = stage[(t - t0) * SPITCH + 3 * nl + 1];
                        const float fz = stage[(t - t0) * SPITCH + 3 * nl + 2];
                        S[0] += x * fx; S[1] += x * fy; S[2] += x * fz;
                        S[3] += y * fx; S[4] += y * fy; S[5] += y * fz;
                        S[6] += z * fx; S[7] += z * fy; S[8] += z * fz;
                        S[9] += fx; S[10] += fy; S[11] += fz;
                    }
                }
#pragma unroll
                for (int v = 0; v < 12; ++v) {
                    S[v] += __shfl_xor(S[v], 1, 64);
                    S[v] += __shfl_xor(S[v], 2, 64);
                }
                if (part == 0) {
                    float* btp = wsf + BT_F + ((size_t)b * HT + t) * 12;
#pragma unroll
                    for (int v = 0; v < 12; ++v) atomicAdd(btp + v, S[v]);
                }
            }
        }
        __syncthreads();   // stage free before next half overwrites it
    }
}

// ---------------------------------------------------------------------------
// compose: one lane per batch (single wave). Sequential over t:
//   H = P^T (C0 P + B); R = polar(H) by 2 Newton iters; M = P(R-I); P = P R.
// ---------------------------------------------------------------------------
__global__ __launch_bounds__(64) void compose_kernel(float* __restrict__ ws)
{
    const int b = threadIdx.x;
    float C0[9], P[9];
#pragma unroll
    for (int v = 0; v < 9; ++v) C0[v] = ws[C0_F + b * 9 + v];
    P[0] = 1.f; P[1] = 0.f; P[2] = 0.f;
    P[3] = 0.f; P[4] = 1.f; P[5] = 0.f;
    P[6] = 0.f; P[7] = 0.f; P[8] = 1.f;

    const float invN = 1.0f / HN_TOOL;
    const float* bt = ws + BT_F + (size_t)b * HT * 12;
    float* mt = ws + MT_F + (size_t)b * HT * 12;

    float4 n0 = *(const float4*)(bt);
    float4 n1 = *(const float4*)(bt + 4);
    float4 n2 = *(const float4*)(bt + 8);

    for (int t = 0; t < HT; ++t) {
        const float Bv[12] = {n0.x, n0.y, n0.z, n0.w, n1.x, n1.y, n1.z, n1.w,
                              n2.x, n2.y, n2.z, n2.w};
        if (t + 1 < HT) {
            const float* nb = bt + (t + 1) * 12;
            n0 = *(const float4*)(nb);
            n1 = *(const float4*)(nb + 4);
            n2 = *(const float4*)(nb + 8);
        }
        // G = C0*P + B
        float G[9];
#pragma unroll
        for (int i = 0; i < 3; ++i)
#pragma unroll
            for (int j = 0; j < 3; ++j)
                G[i * 3 + j] = C0[i * 3 + 0] * P[0 * 3 + j] +
                               C0[i * 3 + 1] * P[1 * 3 + j] +
                               C0[i * 3 + 2] * P[2 * 3 + j] + Bv[i * 3 + j];
        // H = P^T * G
        float X[9];
#pragma unroll
        for (int i = 0; i < 3; ++i)
#pragma unroll
            for (int j = 0; j < 3; ++j)
                X[i * 3 + j] = P[0 * 3 + i] * G[0 * 3 + j] +
                               P[1 * 3 + i] * G[1 * 3 + j] +
                               P[2 * 3 + i] * G[2 * 3 + j];
        const float scl = 3.0f * __builtin_amdgcn_rcpf(X[0] + X[4] + X[8]);
#pragma unroll
        for (int v = 0; v < 9; ++v) X[v] *= scl;
        // 2 Newton polar iters
#pragma unroll
        for (int it = 0; it < 2; ++it) {
            float C[9];
            C[0] =  (X[4] * X[8] - X[5] * X[7]);
            C[1] = -(X[3] * X[8] - X[5] * X[6]);
            C[2] =  (X[3] * X[7] - X[4] * X[6]);
            C[3] = -(X[1] * X[8] - X[2] * X[7]);
            C[4] =  (X[0] * X[8] - X[2] * X[6]);
            C[5] = -(X[0] * X[7] - X[1] * X[6]);
            C[6] =  (X[1] * X[5] - X[2] * X[4]);
            C[7] = -(X[0] * X[5] - X[2] * X[3]);
            C[8] =  (X[0] * X[4] - X[1] * X[3]);
            const float det = X[0] * C[0] + X[1] * C[1] + X[2] * C[2];
            const float rdet = 0.5f * __builtin_amdgcn_rcpf(det);
#pragma unroll
            for (int v = 0; v < 9; ++v) X[v] = 0.5f * X[v] + C[v] * rdet;
        }
        // Pn = P * R (R = X); M = Pn - P
        float Pn[9];
#pragma unroll
        for (int i = 0; i < 3; ++i)
#pragma unroll
            for (int j = 0; j < 3; ++j)
                Pn[i * 3 + j] = P[i * 3 + 0] * X[0 * 3 + j] +
                                P[i * 3 + 1] * X[1 * 3 + j] +
                                P[i * 3 + 2] * X[2 * 3 + j];
        float4 m0, m1, m2;
        m0.x = Pn[0] - P[0]; m0.y = Pn[1] - P[1]; m0.z = Pn[2] - P[2];
        m0.w = Pn[3] - P[3]; m1.x = Pn[4] - P[4]; m1.y = Pn[5] - P[5];
        m1.z = Pn[6] - P[6]; m1.w = Pn[7] - P[7]; m2.x = Pn[8] - P[8];
        m2.y = Bv[9] * invN; m2.z = Bv[10] * invN; m2.w = Bv[11] * invN;
        float* mo = mt + t * 12;
        *(float4*)(mo) = m0;
        *(float4*)(mo + 4) = m1;
        *(float4*)(mo + 8) = m2;
#pragma unroll
        for (int v = 0; v < 9; ++v) P[v] = Pn[v];
    }
}

// ---------------------------------------------------------------------------
// apply: out1[b][t][n] = xc0[b][n] * M[b][t] + mf[b][t]. float4 in, f32x4
// non-temporal out.
// ---------------------------------------------------------------------------
__global__ __launch_bounds__(256) void apply_kernel(
    const float* __restrict__ ws, float* __restrict__ out1)
{
    __shared__ float M[12];
    const int t = blockIdx.x, b = blockIdx.y;
    const int tid = threadIdx.x;
    if (tid < 12) M[tid] = ws[MT_F + (size_t)(b * HT + t) * 12 + tid];
    __syncthreads();

    const int nb = tid * 4;                    // 4 consecutive points/thread
    if (nb < HN_TOOL) {
        const float4* xc4 =
            (const float4*)(ws + XC0_F + (size_t)b * (HN_TOOL * 3) + nb * 3);
        float in12[12], o12[12];
        *(float4*)&in12[0] = xc4[0];
        *(float4*)&in12[4] = xc4[1];
        *(float4*)&in12[8] = xc4[2];
#pragma unroll
        for (int k = 0; k < 4; ++k) {
            const float x = in12[3 * k], y = in12[3 * k + 1], z = in12[3 * k + 2];
            o12[3 * k + 0] = x * M[0] + y * M[3] + z * M[6] + M[9];
            o12[3 * k + 1] = x * M[1] + y * M[4] + z * M[7] + M[10];
            o12[3 * k + 2] = x * M[2] + y * M[5] + z * M[8] + M[11];
        }
        f32x4* ot = (f32x4*)(out1 + ((size_t)(b * HT + t) * HN_TOOL) * 3 + nb * 3);
        __builtin_nontemporal_store(*(f32x4*)&o12[0], ot + 0);
        __builtin_nontemporal_store(*(f32x4*)&o12[4], ot + 1);
        __builtin_nontemporal_store(*(f32x4*)&o12[8], ot + 2);
    }
}

// ---------------------------------------------------------------------------
extern "C" void kernel_launch(void* const* d_in, const int* in_sizes, int n_in,
                              void* d_out, int out_size, void* d_ws, size_t ws_size,
                              hipStream_t stream)
{
    const float* x_feat   = (const float*)d_in[0];
    const float* pos      = (const float*)d_in[1];
    const int*   tool_idx = (const int*)d_in[2];
    const float* W1 = (const float*)d_in[3];
    const float* b1 = (const float*)d_in[4];
    const float* W2 = (const float*)d_in[5];
    const float* b2 = (const float*)d_in[6];
    const float* W3 = (const float*)d_in[7];
    const float* b3 = (const float*)d_in[8];

    float* out1 = (float*)d_out;                               // flow_traj
    float* out2 = out1 + (size_t)HB * HT * HN_TOOL * 3;        // before_svd
    _Float16* wsw = (_Float16*)d_ws;
    float* wsf = (float*)d_ws;

    prep_kernel<<<91, 256, 0, stream>>>(pos, tool_idx, W1, W2, W3, wsw, wsf);
    mlp_mfma_kernel<<<dim3(16, HB), 256, 0, stream>>>(
        x_feat, tool_idx, wsw, b1, b2, b3, out2, wsf);
    compose_kernel<<<1, 64, 0, stream>>>(wsf);
    apply_kernel<<<dim3(HT, HB), 256, 0, stream>>>(wsf, out1);
}

// Round 4
// 287.513 us; speedup vs baseline: 1.1503x; 1.1158x over previous
//
#include <hip/hip_runtime.h>
#include <cstddef>

#define HB 64
#define HN_PER 4096
#define HN_TOOL 1000
#define HD 128
#define HT 50
#define HSCALE 50.0f

typedef _Float16 f16x8 __attribute__((ext_vector_type(8)));
typedef float f32x4 __attribute__((ext_vector_type(4)));

constexpr int TILE_M = 64;
constexpr int APITCH = 136;                     // fp16 LDS row pitch
constexpr int SPITCH = 204;                     // float stage row pitch
constexpr int THALF = 25;                       // timesteps staged per half
constexpr int NBX   = 16;                       // blocks per batch in mlp

// fp16 swizzled weights live in ws halves [0, 53248) = bytes [0, 106496)
constexpr int W1_BASE = 0;
constexpr int W2_BASE = 16384;
constexpr int W3_BASE = 32768;     // 40 frags -> ends at 53248 halves

// float-indexed ws regions (after the fp16 weights)
constexpr int XC0_F = 26624;                    // [B][N][3] centered scaled pos
constexpr int C0_F  = XC0_F + HB * HN_TOOL * 3; // [B][9]  Xc0^T Xc0
constexpr int BT_F  = C0_F + HB * 9;            // [B*T][12] reduced moments
constexpr int MT_F  = BT_F + HB * HT * 12;      // [B*T][12]: P_{t+1}-P_t (9) + mf (3)
constexpr int PART_F = MT_F + HB * HT * 12;     // [B*T][12][NBX] per-block partials

// ---------------------------------------------------------------------------
// Wave64 sum, valid in every lane (row_ror rotations + shfl_xor).
// ---------------------------------------------------------------------------
__device__ __forceinline__ float wave_red_sum(float v)
{
#define DPP_ADD(ctrl)                                                          \
    v += __builtin_bit_cast(float, __builtin_amdgcn_update_dpp(                \
             0, __builtin_bit_cast(int, v), (ctrl), 0xF, 0xF, true));
    DPP_ADD(0x128)   // row_ror:8
    DPP_ADD(0x124)   // row_ror:4
    DPP_ADD(0x122)   // row_ror:2
    DPP_ADD(0x121)   // row_ror:1
#undef DPP_ADD
    v += __shfl_xor(v, 16, 64);
    v += __shfl_xor(v, 32, 64);
    return v;
}

// ---------------------------------------------------------------------------
// prep: blocks 0..63  -> init (gather pos, mu0, xc0, C0) for batch b=blk
//       blocks 64..89 -> weight fp32->fp16 swizzle (4 fragment-waves each)
// ---------------------------------------------------------------------------
__global__ __launch_bounds__(256) void prep_kernel(
    const float* __restrict__ pos,
    const int* __restrict__ tool_idx,
    const float* __restrict__ W1, const float* __restrict__ W2,
    const float* __restrict__ W3,
    _Float16* __restrict__ wsh, float* __restrict__ wsf)
{
    __shared__ float red[4][6];
    const int blk = blockIdx.x;
    const int tid = threadIdx.x;

    if (blk < 64) {
        // ---------------- init for batch b ----------------
        const int b = blk;
        const int lane = tid & 63, wv = tid >> 6;
        const int nb = tid * 4;                 // 4 consecutive points/thread
        const bool act = nb < HN_TOOL;          // threads 0..249 active

        float xv[4], yv[4], zv[4];
        if (act) {
            const int4 i4 = *(const int4*)(tool_idx + b * HN_TOOL + nb);
            const int pi[4] = {i4.x, i4.y, i4.z, i4.w};
#pragma unroll
            for (int s = 0; s < 4; ++s) {
                const float* pp = pos + (size_t)(b * HN_PER + pi[s]) * 3;
                xv[s] = pp[0] * HSCALE;
                yv[s] = pp[1] * HSCALE;
                zv[s] = pp[2] * HSCALE;
            }
        }
        float s0 = 0.f, s1 = 0.f, s2 = 0.f;
        if (act) {
#pragma unroll
            for (int s = 0; s < 4; ++s) { s0 += xv[s]; s1 += yv[s]; s2 += zv[s]; }
        }
        s0 = wave_red_sum(s0); s1 = wave_red_sum(s1); s2 = wave_red_sum(s2);
        if (lane == 0) { red[wv][0] = s0; red[wv][1] = s1; red[wv][2] = s2; }
        __syncthreads();
        const float invN = 1.0f / HN_TOOL;
        const float mux = (red[0][0] + red[1][0] + red[2][0] + red[3][0]) * invN;
        const float muy = (red[0][1] + red[1][1] + red[2][1] + red[3][1]) * invN;
        const float muz = (red[0][2] + red[1][2] + red[2][2] + red[3][2]) * invN;
        __syncthreads();

        float xx = 0.f, xy = 0.f, xz = 0.f, yy = 0.f, yz = 0.f, zz = 0.f;
        if (act) {
            float o[12];
#pragma unroll
            for (int s = 0; s < 4; ++s) {
                const float x = xv[s] - mux, y = yv[s] - muy, z = zv[s] - muz;
                o[3 * s + 0] = x; o[3 * s + 1] = y; o[3 * s + 2] = z;
                xx += x * x; xy += x * y; xz += x * z;
                yy += y * y; yz += y * z; zz += z * z;
            }
            float4* dst = (float4*)(wsf + XC0_F + (size_t)b * (HN_TOOL * 3) + nb * 3);
            dst[0] = *(float4*)&o[0];
            dst[1] = *(float4*)&o[4];
            dst[2] = *(float4*)&o[8];
        }
        float c6[6] = {xx, xy, xz, yy, yz, zz};
#pragma unroll
        for (int v = 0; v < 6; ++v) c6[v] = wave_red_sum(c6[v]);
        if (lane == 0) {
#pragma unroll
            for (int v = 0; v < 6; ++v) red[wv][v] = c6[v];
        }
        __syncthreads();
        if (tid == 0) {
            float g[6];
#pragma unroll
            for (int v = 0; v < 6; ++v)
                g[v] = red[0][v] + red[1][v] + red[2][v] + red[3][v];
            float* c0 = wsf + C0_F + b * 9;
            c0[0] = g[0]; c0[1] = g[1]; c0[2] = g[2];
            c0[3] = g[1]; c0[4] = g[3]; c0[5] = g[4];
            c0[6] = g[2]; c0[7] = g[4]; c0[8] = g[5];
        }
    } else {
        // ---------------- weight conversion ----------------
        const int lane = tid & 63;
        const int f = (blk - 64) * 4 + (tid >> 6);   // 0..103
        const float* W; int ncols, base, fi;
        if (f < 32)       { W = W1; ncols = 128; base = W1_BASE; fi = f; }
        else if (f < 64)  { W = W2; ncols = 128; base = W2_BASE; fi = f - 32; }
        else              { W = W3; ncols = 150; base = W3_BASE; fi = f - 64; }
        const int nt = fi >> 2, kc = fi & 3;
        const int col = nt * 16 + (lane & 15);
        const int k0 = kc * 32 + (lane >> 4) * 8;
        f16x8 v;
#pragma unroll
        for (int j = 0; j < 8; ++j)
            v[j] = (col < ncols) ? (_Float16)W[(size_t)(k0 + j) * ncols + col]
                                 : (_Float16)0.f;
        *(f16x8*)(wsh + ((size_t)(base + (fi * 64 + lane) * 8))) = v;
    }
}

// ---------------------------------------------------------------------------
// Kernel 1: gather -> 3-layer MLP via fp16 MFMA -> LDS-staged coalesced store
// into out2 ([B][T][N][3]) + fused moment partials written NON-atomically to
// PART [b][t][v][bx].
// Grid: dim3(16, 64). NO min-wave launch bound: acc[10] (40 VGPR) must stay
// in registers (launch_bounds(256,7) spilled it to scratch -> VGPR_Count 36).
// ---------------------------------------------------------------------------
__global__ __launch_bounds__(256) void mlp_mfma_kernel(
    const float* __restrict__ x_feat,
    const int* __restrict__ tool_idx,
    const _Float16* __restrict__ Wsw,
    const float* __restrict__ b1, const float* __restrict__ b2,
    const float* __restrict__ b3,
    float* __restrict__ out2, float* __restrict__ wsf)
{
    // hA (64x136 fp16 = 17408 B) lives during the 3 layers;
    // stage (25x204 f32 = 20400 B) aliases it after the last hA read.
    __shared__ __align__(16) char smem[THALF * SPITCH * 4];
    _Float16 (*hA)[APITCH] = (_Float16 (*)[APITCH])smem;
    float* stage = (float*)smem;

    const int tid = threadIdx.x;
    const int lane = tid & 63, w = tid >> 6;
    const int lm = lane & 15, quad = lane >> 4;
    const int m0 = w * 16;
    const int bx = blockIdx.x;                 // 0..15 within batch
    const int b  = blockIdx.y;                 // batch
    const int n0 = bx * TILE_M;

    {
        const int i = tid >> 2;
        const int c0 = (tid & 3) * 32;
        const int n = n0 + i;
        const int nc = (n < HN_TOOL) ? n : (HN_TOOL - 1);   // clamp pad rows
        const int p = tool_idx[b * HN_TOOL + nc];
        const float4* src =
            (const float4*)(x_feat + (size_t)(b * HN_PER + p) * HD + c0);
#pragma unroll
        for (int fq = 0; fq < 4; ++fq) {
            const float4 u = src[2 * fq], v = src[2 * fq + 1];
            f16x8 h = {(_Float16)u.x, (_Float16)u.y, (_Float16)u.z, (_Float16)u.w,
                       (_Float16)v.x, (_Float16)v.y, (_Float16)v.z, (_Float16)v.w};
            *(f16x8*)&hA[i][c0 + fq * 8] = h;
        }
    }
    __syncthreads();

    // layers 1,2: each wave owns its 16 rows end-to-end (no cross-wave dep)
#pragma unroll
    for (int layer = 0; layer < 2; ++layer) {
        const _Float16* wb = Wsw + (layer ? W2_BASE : W1_BASE);
        const float* bias = layer ? b2 : b1;
        f16x8 afr[4];
#pragma unroll
        for (int kc = 0; kc < 4; ++kc)
            afr[kc] = *(const f16x8*)&hA[m0 + lm][kc * 32 + quad * 8];
        f32x4 acc[8];
#pragma unroll
        for (int nt = 0; nt < 8; ++nt) acc[nt] = (f32x4){0.f, 0.f, 0.f, 0.f};
#pragma unroll
        for (int kc = 0; kc < 4; ++kc)
#pragma unroll
            for (int nt = 0; nt < 8; ++nt) {
                const f16x8 bf = *(const f16x8*)(wb + (size_t)((nt * 4 + kc) * 64 + lane) * 8);
                acc[nt] = __builtin_amdgcn_mfma_f32_16x16x32_f16(afr[kc], bf, acc[nt], 0, 0, 0);
            }
#pragma unroll
        for (int nt = 0; nt < 8; ++nt) {
            const float bb = bias[nt * 16 + lm];
#pragma unroll
            for (int r = 0; r < 4; ++r)
                hA[m0 + quad * 4 + r][nt * 16 + lm] =
                    (_Float16)fmaxf(acc[nt][r] + bb, 0.f);
        }
    }

    // layer 3
    f32x4 acc[10];
    {
        f16x8 afr[4];
#pragma unroll
        for (int kc = 0; kc < 4; ++kc)
            afr[kc] = *(const f16x8*)&hA[m0 + lm][kc * 32 + quad * 8];
        __syncthreads();   // all hA reads done before stage aliases it
#pragma unroll
        for (int nt = 0; nt < 10; ++nt) acc[nt] = (f32x4){0.f, 0.f, 0.f, 0.f};
#pragma unroll
        for (int kc = 0; kc < 4; ++kc)
#pragma unroll
            for (int nt = 0; nt < 10; ++nt) {
                const f16x8 bf = *(const f16x8*)(Wsw + W3_BASE + (size_t)((nt * 4 + kc) * 64 + lane) * 8);
                acc[nt] = __builtin_amdgcn_mfma_f32_16x16x32_f16(afr[kc], bf, acc[nt], 0, 0, 0);
            }
    }

    // epilogue in two halves of 25 timesteps each
    const int V = (bx == 15) ? (HN_TOOL - 15 * TILE_M) : TILE_M;   // 40 or 64
    const int nf4 = (V * 3) >> 2;                                   // 30 or 48
#pragma unroll
    for (int h = 0; h < 2; ++h) {
        const int t0 = h * THALF;
        // write flow values for this half transposed into stage[t-t0][i*3+c]
#pragma unroll
        for (int nt = 0; nt < 10; ++nt) {
            const int j = nt * 16 + lm;
            if (j < 150) {
                const int t = j / 3, c = j - 3 * t;
                if (t >= t0 && t < t0 + THALF) {
                    const float bb = b3[j];
#pragma unroll
                    for (int r = 0; r < 4; ++r)
                        stage[(t - t0) * SPITCH + (m0 + quad * 4 + r) * 3 + c] =
                            acc[nt][r] + bb;
                }
            }
        }
        __syncthreads();

        // coalesced non-temporal out2 store for this half
        {
            float* ob = out2 + (size_t)b * HT * (HN_TOOL * 3) + (size_t)n0 * 3;
            for (int t = t0 + w; t < t0 + THALF; t += 4) {
                if (lane < nf4) {
                    const f32x4 v =
                        *(const f32x4*)&stage[(t - t0) * SPITCH + lane * 4];
                    __builtin_nontemporal_store(
                        v, (f32x4*)(ob + (size_t)t * (HN_TOOL * 3)) + lane);
                }
            }
        }

        // fused moment reduction for this half: 4 threads (16 rows each) per t
        if (tid < 4 * HT) {
            const int t = tid >> 2;
            if (t >= t0 && t < t0 + THALF) {
                const int part = tid & 3;
                const float* xc =
                    wsf + XC0_F + (size_t)b * (HN_TOOL * 3) + (size_t)n0 * 3;
                float S[12];
#pragma unroll
                for (int v = 0; v < 12; ++v) S[v] = 0.f;
#pragma unroll
                for (int rr = 0; rr < 16; ++rr) {
                    const int nl = part * 16 + rr;
                    if (n0 + nl < HN_TOOL) {
                        const float x = xc[3 * nl + 0], y = xc[3 * nl + 1],
                                    z = xc[3 * nl + 2];
                        const float fx = stage[(t - t0) * SPITCH + 3 * nl + 0];
                        const float fy = stage[(t - t0) * SPITCH + 3 * nl + 1];
                        const float fz = stage[(t - t0) * SPITCH + 3 * nl + 2];
                        S[0] += x * fx; S[1] += x * fy; S[2] += x * fz;
                        S[3] += y * fx; S[4] += y * fy; S[5] += y * fz;
                        S[6] += z * fx; S[7] += z * fy; S[8] += z * fz;
                        S[9] += fx; S[10] += fy; S[11] += fz;
                    }
                }
#pragma unroll
                for (int v = 0; v < 12; ++v) {
                    S[v] += __shfl_xor(S[v], 1, 64);
                    S[v] += __shfl_xor(S[v], 2, 64);
                }
                // non-atomic partial write: PART [b][t][v][bx]
                if (part == 0) {
                    float* pp = wsf + PART_F +
                                (((size_t)b * HT + t) * 12) * NBX + bx;
#pragma unroll
                    for (int v = 0; v < 12; ++v) pp[v * NBX] = S[v];
                }
            }
        }
        __syncthreads();   // stage free before next half overwrites it
    }
}

// ---------------------------------------------------------------------------
// reduce_bt: BT[b][t][v] = sum over bx of PART[b][t][v][bx].
// 38400 outputs; one thread each; 16 consecutive floats read via 4x float4.
// ---------------------------------------------------------------------------
__global__ __launch_bounds__(512) void reduce_bt_kernel(float* __restrict__ ws)
{
    const int o = blockIdx.x * 512 + threadIdx.x;   // flat (b*50+t)*12+v
    if (o >= HB * HT * 12) return;
    const float4* p = (const float4*)(ws + PART_F + (size_t)o * NBX);
    const float4 a = p[0], bq = p[1], c = p[2], d = p[3];
    const float s = ((a.x + a.y) + (a.z + a.w)) + ((bq.x + bq.y) + (bq.z + bq.w)) +
                    ((c.x + c.y) + (c.z + c.w)) + ((d.x + d.y) + (d.z + d.w));
    ws[BT_F + o] = s;
}

// ---------------------------------------------------------------------------
// compose: one lane per batch (single wave). Sequential over t:
//   H = P^T (C0 P + B); R = polar(H) by 2 Newton iters; M = P(R-I); P = P R.
// ---------------------------------------------------------------------------
__global__ __launch_bounds__(64) void compose_kernel(float* __restrict__ ws)
{
    const int b = threadIdx.x;
    float C0[9], P[9];
#pragma unroll
    for (int v = 0; v < 9; ++v) C0[v] = ws[C0_F + b * 9 + v];
    P[0] = 1.f; P[1] = 0.f; P[2] = 0.f;
    P[3] = 0.f; P[4] = 1.f; P[5] = 0.f;
    P[6] = 0.f; P[7] = 0.f; P[8] = 1.f;

    const float invN = 1.0f / HN_TOOL;
    const float* bt = ws + BT_F + (size_t)b * HT * 12;
    float* mt = ws + MT_F + (size_t)b * HT * 12;

    float4 n0 = *(const float4*)(bt);
    float4 n1 = *(const float4*)(bt + 4);
    float4 n2 = *(const float4*)(bt + 8);

    for (int t = 0; t < HT; ++t) {
        const float Bv[12] = {n0.x, n0.y, n0.z, n0.w, n1.x, n1.y, n1.z, n1.w,
                              n2.x, n2.y, n2.z, n2.w};
        if (t + 1 < HT) {
            const float* nb = bt + (t + 1) * 12;
            n0 = *(const float4*)(nb);
            n1 = *(const float4*)(nb + 4);
            n2 = *(const float4*)(nb + 8);
        }
        // G = C0*P + B
        float G[9];
#pragma unroll
        for (int i = 0; i < 3; ++i)
#pragma unroll
            for (int j = 0; j < 3; ++j)
                G[i * 3 + j] = C0[i * 3 + 0] * P[0 * 3 + j] +
                               C0[i * 3 + 1] * P[1 * 3 + j] +
                               C0[i * 3 + 2] * P[2 * 3 + j] + Bv[i * 3 + j];
        // H = P^T * G
        float X[9];
#pragma unroll
        for (int i = 0; i < 3; ++i)
#pragma unroll
            for (int j = 0; j < 3; ++j)
                X[i * 3 + j] = P[0 * 3 + i] * G[0 * 3 + j] +
                               P[1 * 3 + i] * G[1 * 3 + j] +
                               P[2 * 3 + i] * G[2 * 3 + j];
        const float scl = 3.0f * __builtin_amdgcn_rcpf(X[0] + X[4] + X[8]);
#pragma unroll
        for (int v = 0; v < 9; ++v) X[v] *= scl;
        // 2 Newton polar iters
#pragma unroll
        for (int it = 0; it < 2; ++it) {
            float C[9];
            C[0] =  (X[4] * X[8] - X[5] * X[7]);
            C[1] = -(X[3] * X[8] - X[5] * X[6]);
            C[2] =  (X[3] * X[7] - X[4] * X[6]);
            C[3] = -(X[1] * X[8] - X[2] * X[7]);
            C[4] =  (X[0] * X[8] - X[2] * X[6]);
            C[5] = -(X[0] * X[7] - X[1] * X[6]);
            C[6] =  (X[1] * X[5] - X[2] * X[4]);
            C[7] = -(X[0] * X[5] - X[2] * X[3]);
            C[8] =  (X[0] * X[4] - X[1] * X[3]);
            const float det = X[0] * C[0] + X[1] * C[1] + X[2] * C[2];
            const float rdet = 0.5f * __builtin_amdgcn_rcpf(det);
#pragma unroll
            for (int v = 0; v < 9; ++v) X[v] = 0.5f * X[v] + C[v] * rdet;
        }
        // Pn = P * R (R = X); M = Pn - P
        float Pn[9];
#pragma unroll
        for (int i = 0; i < 3; ++i)
#pragma unroll
            for (int j = 0; j < 3; ++j)
                Pn[i * 3 + j] = P[i * 3 + 0] * X[0 * 3 + j] +
                                P[i * 3 + 1] * X[1 * 3 + j] +
                                P[i * 3 + 2] * X[2 * 3 + j];
        float4 m0, m1, m2;
        m0.x = Pn[0] - P[0]; m0.y = Pn[1] - P[1]; m0.z = Pn[2] - P[2];
        m0.w = Pn[3] - P[3]; m1.x = Pn[4] - P[4]; m1.y = Pn[5] - P[5];
        m1.z = Pn[6] - P[6]; m1.w = Pn[7] - P[7]; m2.x = Pn[8] - P[8];
        m2.y = Bv[9] * invN; m2.z = Bv[10] * invN; m2.w = Bv[11] * invN;
        float* mo = mt + t * 12;
        *(float4*)(mo) = m0;
        *(float4*)(mo + 4) = m1;
        *(float4*)(mo + 8) = m2;
#pragma unroll
        for (int v = 0; v < 9; ++v) P[v] = Pn[v];
    }
}

// ---------------------------------------------------------------------------
// apply: out1[b][t][n] = xc0[b][n] * M[b][t] + mf[b][t]. float4 in, f32x4
// non-temporal out.
// ---------------------------------------------------------------------------
__global__ __launch_bounds__(256) void apply_kernel(
    const float* __restrict__ ws, float* __restrict__ out1)
{
    __shared__ float M[12];
    const int t = blockIdx.x, b = blockIdx.y;
    const int tid = threadIdx.x;
    if (tid < 12) M[tid] = ws[MT_F + (size_t)(b * HT + t) * 12 + tid];
    __syncthreads();

    const int nb = tid * 4;                    // 4 consecutive points/thread
    if (nb < HN_TOOL) {
        const float4* xc4 =
            (const float4*)(ws + XC0_F + (size_t)b * (HN_TOOL * 3) + nb * 3);
        float in12[12], o12[12];
        *(float4*)&in12[0] = xc4[0];
        *(float4*)&in12[4] = xc4[1];
        *(float4*)&in12[8] = xc4[2];
#pragma unroll
        for (int k = 0; k < 4; ++k) {
            const float x = in12[3 * k], y = in12[3 * k + 1], z = in12[3 * k + 2];
            o12[3 * k + 0] = x * M[0] + y * M[3] + z * M[6] + M[9];
            o12[3 * k + 1] = x * M[1] + y * M[4] + z * M[7] + M[10];
            o12[3 * k + 2] = x * M[2] + y * M[5] + z * M[8] + M[11];
        }
        f32x4* ot = (f32x4*)(out1 + ((size_t)(b * HT + t) * HN_TOOL) * 3 + nb * 3);
        __builtin_nontemporal_store(*(f32x4*)&o12[0], ot + 0);
        __builtin_nontemporal_store(*(f32x4*)&o12[4], ot + 1);
        __builtin_nontemporal_store(*(f32x4*)&o12[8], ot + 2);
    }
}

// ---------------------------------------------------------------------------
extern "C" void kernel_launch(void* const* d_in, const int* in_sizes, int n_in,
                              void* d_out, int out_size, void* d_ws, size_t ws_size,
                              hipStream_t stream)
{
    const float* x_feat   = (const float*)d_in[0];
    const float* pos      = (const float*)d_in[1];
    const int*   tool_idx = (const int*)d_in[2];
    const float* W1 = (const float*)d_in[3];
    const float* b1 = (const float*)d_in[4];
    const float* W2 = (const float*)d_in[5];
    const float* b2 = (const float*)d_in[6];
    const float* W3 = (const float*)d_in[7];
    const float* b3 = (const float*)d_in[8];

    float* out1 = (float*)d_out;                               // flow_traj
    float* out2 = out1 + (size_t)HB * HT * HN_TOOL * 3;        // before_svd
    _Float16* wsw = (_Float16*)d_ws;
    float* wsf = (float*)d_ws;

    prep_kernel<<<90, 256, 0, stream>>>(pos, tool_idx, W1, W2, W3, wsw, wsf);
    mlp_mfma_kernel<<<dim3(NBX, HB), 256, 0, stream>>>(
        x_feat, tool_idx, wsw, b1, b2, b3, out2, wsf);
    reduce_bt_kernel<<<75, 512, 0, stream>>>(wsf);
    compose_kernel<<<1, 64, 0, stream>>>(wsf);
    apply_kernel<<<dim3(HT, HB), 256, 0, stream>>>(wsf, out1);
}